// Round 4
// baseline (635.223 us; speedup 1.0000x reference)
//
#include <hip/hip_runtime.h>
#include <hip/hip_bf16.h>

#define BB   64
#define NTOT 800000
#define NF4  200000          // NTOT / 4
#define NP   128
#define NH1  256
#define NH2  128
#define NC   32
#define EPSV 1e-5f
#define BG   8               // batches per block (batch split 8-ways)

typedef float fx4 __attribute__((ext_vector_type(4)));

__device__ __forceinline__ int bitrev3(int l) {
    return ((l & 1) << 2) | (l & 2) | ((l & 4) >> 2);
}

__device__ __forceinline__ float dot4(fx4 a, fx4 b) {
    return fmaf(a[0], b[0], fmaf(a[1], b[1], fmaf(a[2], b[2], a[3] * b[3])));
}

template <int C, int M>
__device__ __forceinline__ void red_step(float* v, int lane) {
    const bool hi = (lane & M) != 0;
    #pragma unroll
    for (int j = 0; j < C / 2; ++j) {
        float mine  = hi ? v[j + C / 2] : v[j];
        float other = hi ? v[j]         : v[j + C / 2];
        v[j] = mine + __shfl_xor(other, M);
    }
}

// ---------------------------------------------------------------------------
// Scatter-reduce: WX[b, idx[n]] += x[b,n] * w[n]     (idx sorted)
// Each thread: 2 consecutive quad-columns x 8 batches = 16 float4 loads,
// ALL pinned live at once via asm -> 16 outstanding global_load_dwordx4
// (16KB/wave in flight). One transpose-reduce + one atomic instr per wave.
// ---------------------------------------------------------------------------
__global__ __launch_bounds__(256) void k_scatter(
    const float* __restrict__ x, const float* __restrict__ w,
    const int* __restrict__ idx, float* __restrict__ WX)
{
    const int t    = threadIdx.x;
    const int lane = t & 63;
    const int n4a  = blockIdx.x * 512 + t;        // always < NF4 (grid sized so)
    int       n4b  = n4a + 256;
    const bool bval = (n4b < NF4);
    if (!bval) n4b = n4a;                         // clamp: zero-weight below
    const int b0 = blockIdx.y * BG;

    const fx4*  __restrict__ w4 = reinterpret_cast<const fx4*>(w);
    const int4* __restrict__ p4 = reinterpret_cast<const int4*>(idx);
    const fx4  wa = w4[n4a];
    const fx4  wb = bval ? w4[n4b] : (fx4)(0.f);
    const int4 pa = p4[n4a];
    const int4 pb = bval ? p4[n4b] : pa;

    const int  fp  = __builtin_amdgcn_readfirstlane(pa.x);
    const bool uni = (__ballot(((pa.x == pa.w) && (pb.x == pb.w) &&
                                (pa.x == fp) && (pb.x == fp)) ? 1 : 0) == ~0ull);

    const fx4* __restrict__ xa = reinterpret_cast<const fx4*>(x) + (size_t)b0 * NF4 + n4a;
    const fx4* __restrict__ xb = reinterpret_cast<const fx4*>(x) + (size_t)b0 * NF4 + n4b;

    if (uni) {
        fx4 a0 = xa[0];
        fx4 a1 = xa[(size_t)1 * NF4];
        fx4 a2 = xa[(size_t)2 * NF4];
        fx4 a3 = xa[(size_t)3 * NF4];
        fx4 a4 = xa[(size_t)4 * NF4];
        fx4 a5 = xa[(size_t)5 * NF4];
        fx4 a6 = xa[(size_t)6 * NF4];
        fx4 a7 = xa[(size_t)7 * NF4];
        fx4 c0 = xb[0];
        fx4 c1 = xb[(size_t)1 * NF4];
        fx4 c2 = xb[(size_t)2 * NF4];
        fx4 c3 = xb[(size_t)3 * NF4];
        fx4 c4 = xb[(size_t)4 * NF4];
        fx4 c5 = xb[(size_t)5 * NF4];
        fx4 c6 = xb[(size_t)6 * NF4];
        fx4 c7 = xb[(size_t)7 * NF4];
        // Pin all 16 float4 live at once: forces 16 loads in flight.
        asm volatile("" : "+v"(a0), "+v"(a1), "+v"(a2), "+v"(a3),
                          "+v"(a4), "+v"(a5), "+v"(a6), "+v"(a7),
                          "+v"(c0), "+v"(c1), "+v"(c2), "+v"(c3),
                          "+v"(c4), "+v"(c5), "+v"(c6), "+v"(c7));
        float v[BG];
        v[0] = dot4(a0, wa) + dot4(c0, wb);
        v[1] = dot4(a1, wa) + dot4(c1, wb);
        v[2] = dot4(a2, wa) + dot4(c2, wb);
        v[3] = dot4(a3, wa) + dot4(c3, wb);
        v[4] = dot4(a4, wa) + dot4(c4, wb);
        v[5] = dot4(a5, wa) + dot4(c5, wb);
        v[6] = dot4(a6, wa) + dot4(c6, wb);
        v[7] = dot4(a7, wa) + dot4(c7, wb);
        red_step<8, 1>(v, lane);
        red_step<4, 2>(v, lane);
        red_step<2, 4>(v, lane);
        float s = v[0];
        s += __shfl_xor(s, 8);
        s += __shfl_xor(s, 16);
        s += __shfl_xor(s, 32);
        if (lane < 8)
            atomicAdd(&WX[(b0 + bitrev3(lane)) * NP + fp], s);
    } else {  // pathway boundary inside wave's 2KB span (rare)
        #pragma unroll
        for (int i = 0; i < BG; ++i) {
            fx4 xra = xa[(size_t)i * NF4];
            fx4 xrb = xb[(size_t)i * NF4];
            float* row = &WX[(b0 + i) * NP];
            if (pa.x == pa.w) {
                atomicAdd(&row[pa.x], dot4(xra, wa));
            } else {
                atomicAdd(&row[pa.x], xra[0] * wa[0]);
                atomicAdd(&row[pa.y], xra[1] * wa[1]);
                atomicAdd(&row[pa.z], xra[2] * wa[2]);
                atomicAdd(&row[pa.w], xra[3] * wa[3]);
            }
            if (pb.x == pb.w) {
                atomicAdd(&row[pb.x], dot4(xrb, wb));
            } else {
                atomicAdd(&row[pb.x], xrb[0] * wb[0]);
                atomicAdd(&row[pb.y], xrb[1] * wb[1]);
                atomicAdd(&row[pb.z], xrb[2] * wb[2]);
                atomicAdd(&row[pb.w], xrb[3] * wb[3]);
            }
        }
    }
}

// ---------------------------------------------------------------------------
// BN0 (batch stats over axis 0) + CancelOut sigmoid gate. One block, 128 thr.
// ---------------------------------------------------------------------------
__global__ void k_bn0(const float* __restrict__ WX,
                      const float* __restrict__ co_w,
                      const float* __restrict__ g,
                      const float* __restrict__ beta,
                      float* __restrict__ Z)
{
    const int p = threadIdx.x;  // 0..127
    float sum = 0.f, sq = 0.f;
    for (int b = 0; b < BB; ++b) {
        float r = fmaxf(WX[b * NP + p], 0.f);
        sum += r; sq += r * r;
    }
    const float m   = sum * (1.f / BB);
    const float var = sq * (1.f / BB) - m * m;
    const float sc  = rsqrtf(var + EPSV) * g[p];
    const float bt  = beta[p];
    const float sig = 1.f / (1.f + expf(-co_w[p]));
    for (int b = 0; b < BB; ++b) {
        float r = fmaxf(WX[b * NP + p], 0.f);
        Z[b * NP + p] = ((r - m) * sc + bt) * sig;
    }
}

// ---------------------------------------------------------------------------
// Linear -> ReLU -> BN(batch stats). One block per output column j,
// 64 threads = 1 wave = the batch dim -> BN stats via wave shuffle.
// ---------------------------------------------------------------------------
template <int K, int NOUT>
__global__ void k_fc_bn(const float* __restrict__ in,    // [BB, K]
                        const float* __restrict__ W,     // [K, NOUT]
                        const float* __restrict__ bias,
                        const float* __restrict__ g,
                        const float* __restrict__ beta,
                        float* __restrict__ out)         // [BB, NOUT]
{
    const int j = blockIdx.x;
    const int b = threadIdx.x;  // 0..63
    const float* __restrict__ row = in + b * K;
    float acc = bias[j];
    #pragma unroll 8
    for (int k = 0; k < K; ++k)
        acc = fmaf(row[k], W[k * NOUT + j], acc);
    acc = fmaxf(acc, 0.f);
    float s = acc, q = acc * acc;
    #pragma unroll
    for (int off = 32; off > 0; off >>= 1) {
        s += __shfl_xor(s, off);
        q += __shfl_xor(q, off);
    }
    const float m   = s * (1.f / BB);
    const float var = q * (1.f / BB) - m * m;
    out[b * NOUT + j] = (acc - m) * rsqrtf(var + EPSV) * g[j] + beta[j];
}

// ---------------------------------------------------------------------------
// Final Linear + row softmax. One block per batch row, 32 threads = classes.
// ---------------------------------------------------------------------------
__global__ void k_head(const float* __restrict__ h,   // [BB, NH2]
                       const float* __restrict__ Wo,  // [NH2, NC]
                       const float* __restrict__ bo,
                       float* __restrict__ y)         // [BB, NC]
{
    const int b = blockIdx.x;
    const int c = threadIdx.x;  // 0..31
    const float* __restrict__ row = h + b * NH2;
    float acc = bo[c];
    #pragma unroll 8
    for (int k = 0; k < NH2; ++k)
        acc = fmaf(row[k], Wo[k * NC + c], acc);
    float mx = acc;
    #pragma unroll
    for (int off = 16; off > 0; off >>= 1)
        mx = fmaxf(mx, __shfl_xor(mx, off));
    const float e = expf(acc - mx);
    float s = e;
    #pragma unroll
    for (int off = 16; off > 0; off >>= 1)
        s += __shfl_xor(s, off);
    y[b * NC + c] = e / s;
}

// ---------------------------------------------------------------------------
extern "C" void kernel_launch(void* const* d_in, const int* in_sizes, int n_in,
                              void* d_out, int out_size, void* d_ws, size_t ws_size,
                              hipStream_t stream)
{
    const float* x    = (const float*)d_in[0];
    const float* w    = (const float*)d_in[1];
    const float* co_w = (const float*)d_in[2];
    const float* bn0g = (const float*)d_in[3];
    const float* bn0b = (const float*)d_in[4];
    const float* W1   = (const float*)d_in[5];
    const float* b1   = (const float*)d_in[6];
    const float* bn1g = (const float*)d_in[7];
    const float* bn1b = (const float*)d_in[8];
    const float* W2   = (const float*)d_in[9];
    const float* b2   = (const float*)d_in[10];
    const float* bn2g = (const float*)d_in[11];
    const float* bn2b = (const float*)d_in[12];
    const float* Wo   = (const float*)d_in[13];
    const float* bo   = (const float*)d_in[14];
    const int*   idx  = (const int*)d_in[15];

    float* out = (float*)d_out;
    float* y   = out;               // [64, 32]  (output 0)
    float* Z   = out + BB * NC;     // [64, 128] (output 1)

    float* WX = (float*)d_ws;       // 8192 f32
    float* h1 = WX + BB * NP;       // 16384 f32
    float* h2 = h1 + BB * NH1;      // 8192 f32

    hipMemsetAsync(WX, 0, BB * NP * sizeof(float), stream);
    dim3 sgrid((NF4 + 511) / 512, BB / BG);
    k_scatter<<<sgrid, 256, 0, stream>>>(x, w, idx, WX);
    k_bn0<<<1, NP, 0, stream>>>(WX, co_w, bn0g, bn0b, Z);
    k_fc_bn<NP, NH1><<<NH1, BB, 0, stream>>>(Z, W1, b1, bn1g, bn1b, h1);
    k_fc_bn<NH1, NH2><<<NH2, BB, 0, stream>>>(h1, W2, b2, bn2g, bn2b, h2);
    k_head<<<BB, NC, 0, stream>>>(h2, Wo, bo, y);
}

// Round 5
// 158.883 us; speedup vs baseline: 3.9980x; 3.9980x over previous
//
#include <hip/hip_runtime.h>
#include <hip/hip_bf16.h>

#define BB     64
#define NTOT   800000
#define NF4    200000        // NTOT / 4
#define CHUNKS (NF4 / 64)    // 3125 chunks of 64 float4 per batch-row
#define NP     128
#define NH1    256
#define NH2    128
#define NC     32
#define EPSV   1e-5f

typedef float fx4 __attribute__((ext_vector_type(4)));

__device__ __forceinline__ float dot4(fx4 a, fx4 b) {
    return fmaf(a[0], b[0], fmaf(a[1], b[1], fmaf(a[2], b[2], a[3] * b[3])));
}

__device__ __forceinline__ int bitrev2(int l) {
    return ((l & 1) << 1) | ((l >> 1) & 1);
}

template <int C, int M>
__device__ __forceinline__ void red_step(float* v, int lane) {
    const bool hi = (lane & M) != 0;
    #pragma unroll
    for (int j = 0; j < C / 2; ++j) {
        float mine  = hi ? v[j + C / 2] : v[j];
        float other = hi ? v[j]         : v[j + C / 2];
        v[j] = mine + __shfl_xor(other, M);
    }
}

// ---------------------------------------------------------------------------
// Scatter-reduce: WX[b, idx[n]] += x[b,n] * w[n]     (idx sorted)
// Persistent grid-stride waves. One iteration = one (4-batch group, 64-quad
// chunk): w/idx loaded once, 4 independent x float4 loads, 4 dots,
// 7-shuffle transpose reduce, 4 atomics (lanes 0-3). Two iterations
// processed per loop trip so the second's loads are in flight during the
// first's shuffle chain. No asm pinning — TLP (16 waves/CU) does the rest.
// ---------------------------------------------------------------------------
__global__ __launch_bounds__(256, 2) void k_scatter(
    const float* __restrict__ x, const float* __restrict__ w,
    const int* __restrict__ idx, float* __restrict__ WX)
{
    const int lane = threadIdx.x & 63;
    const int wid  = (blockIdx.x * 256 + threadIdx.x) >> 6;
    const int nw   = (gridDim.x * 256) >> 6;
    const int total = 16 * CHUNKS;                    // 16 batch-groups x chunks

    const fx4*  __restrict__ w4 = reinterpret_cast<const fx4*>(w);
    const int4* __restrict__ p4 = reinterpret_cast<const int4*>(idx);
    const fx4*  __restrict__ x4 = reinterpret_cast<const fx4*>(x);

    for (int it0 = wid; it0 < total; it0 += 2 * nw) {
        const int  itB0 = it0 + nw;
        const bool hasB = (itB0 < total);             // wave-uniform
        const int  itB  = hasB ? itB0 : it0;

        const int bgA = (it0 & 15) * 4, chA = it0 >> 4;
        const int bgB = (itB & 15) * 4, chB = itB >> 4;
        const int n4A = chA * 64 + lane;
        const int n4B = chB * 64 + lane;

        // ---- issue all loads for both iterations ----
        const fx4  wA = w4[n4A];
        const int4 pA = p4[n4A];
        fx4 xA0 = x4[(size_t)(bgA + 0) * NF4 + n4A];
        fx4 xA1 = x4[(size_t)(bgA + 1) * NF4 + n4A];
        fx4 xA2 = x4[(size_t)(bgA + 2) * NF4 + n4A];
        fx4 xA3 = x4[(size_t)(bgA + 3) * NF4 + n4A];
        const fx4  wBv = w4[n4B];
        const int4 pB  = p4[n4B];
        fx4 xB0 = x4[(size_t)(bgB + 0) * NF4 + n4B];
        fx4 xB1 = x4[(size_t)(bgB + 1) * NF4 + n4B];
        fx4 xB2 = x4[(size_t)(bgB + 2) * NF4 + n4B];
        fx4 xB3 = x4[(size_t)(bgB + 3) * NF4 + n4B];

        // ---- process A ----
        {
            const int  fp  = __builtin_amdgcn_readfirstlane(pA.x);
            const bool qok = (pA.x == pA.w) && (pA.x == fp);
            float v[4];
            v[0] = dot4(xA0, wA); v[1] = dot4(xA1, wA);
            v[2] = dot4(xA2, wA); v[3] = dot4(xA3, wA);
            if (__ballot(qok ? 1 : 0) == ~0ull) {
                red_step<4, 1>(v, lane);
                red_step<2, 2>(v, lane);
                float s = v[0];
                s += __shfl_xor(s, 4);
                s += __shfl_xor(s, 8);
                s += __shfl_xor(s, 16);
                s += __shfl_xor(s, 32);
                if (lane < 4)
                    atomicAdd(&WX[(bgA + bitrev2(lane)) * NP + fp], s);
            } else {
                const fx4 xs[4] = {xA0, xA1, xA2, xA3};
                #pragma unroll
                for (int i = 0; i < 4; ++i) {
                    float* row = &WX[(bgA + i) * NP];
                    if (pA.x == pA.w) {
                        atomicAdd(&row[pA.x], v[i]);
                    } else {
                        atomicAdd(&row[pA.x], xs[i][0] * wA[0]);
                        atomicAdd(&row[pA.y], xs[i][1] * wA[1]);
                        atomicAdd(&row[pA.z], xs[i][2] * wA[2]);
                        atomicAdd(&row[pA.w], xs[i][3] * wA[3]);
                    }
                }
            }
        }

        // ---- process B ----
        if (hasB) {
            const int  fp  = __builtin_amdgcn_readfirstlane(pB.x);
            const bool qok = (pB.x == pB.w) && (pB.x == fp);
            float v[4];
            v[0] = dot4(xB0, wBv); v[1] = dot4(xB1, wBv);
            v[2] = dot4(xB2, wBv); v[3] = dot4(xB3, wBv);
            if (__ballot(qok ? 1 : 0) == ~0ull) {
                red_step<4, 1>(v, lane);
                red_step<2, 2>(v, lane);
                float s = v[0];
                s += __shfl_xor(s, 4);
                s += __shfl_xor(s, 8);
                s += __shfl_xor(s, 16);
                s += __shfl_xor(s, 32);
                if (lane < 4)
                    atomicAdd(&WX[(bgB + bitrev2(lane)) * NP + fp], s);
            } else {
                const fx4 xs[4] = {xB0, xB1, xB2, xB3};
                #pragma unroll
                for (int i = 0; i < 4; ++i) {
                    float* row = &WX[(bgB + i) * NP];
                    if (pB.x == pB.w) {
                        atomicAdd(&row[pB.x], v[i]);
                    } else {
                        atomicAdd(&row[pB.x], xs[i][0] * wBv[0]);
                        atomicAdd(&row[pB.y], xs[i][1] * wBv[1]);
                        atomicAdd(&row[pB.z], xs[i][2] * wBv[2]);
                        atomicAdd(&row[pB.w], xs[i][3] * wBv[3]);
                    }
                }
            }
        }
    }
}

// ---------------------------------------------------------------------------
// BN0 (batch stats over axis 0) + CancelOut sigmoid gate. One block, 128 thr.
// ---------------------------------------------------------------------------
__global__ void k_bn0(const float* __restrict__ WX,
                      const float* __restrict__ co_w,
                      const float* __restrict__ g,
                      const float* __restrict__ beta,
                      float* __restrict__ Z)
{
    const int p = threadIdx.x;  // 0..127
    float sum = 0.f, sq = 0.f;
    for (int b = 0; b < BB; ++b) {
        float r = fmaxf(WX[b * NP + p], 0.f);
        sum += r; sq += r * r;
    }
    const float m   = sum * (1.f / BB);
    const float var = sq * (1.f / BB) - m * m;
    const float sc  = rsqrtf(var + EPSV) * g[p];
    const float bt  = beta[p];
    const float sig = 1.f / (1.f + expf(-co_w[p]));
    for (int b = 0; b < BB; ++b) {
        float r = fmaxf(WX[b * NP + p], 0.f);
        Z[b * NP + p] = ((r - m) * sc + bt) * sig;
    }
}

// ---------------------------------------------------------------------------
// Linear -> ReLU -> BN(batch stats). One block per output column j,
// 64 threads = 1 wave = the batch dim -> BN stats via wave shuffle.
// ---------------------------------------------------------------------------
template <int K, int NOUT>
__global__ void k_fc_bn(const float* __restrict__ in,    // [BB, K]
                        const float* __restrict__ W,     // [K, NOUT]
                        const float* __restrict__ bias,
                        const float* __restrict__ g,
                        const float* __restrict__ beta,
                        float* __restrict__ out)         // [BB, NOUT]
{
    const int j = blockIdx.x;
    const int b = threadIdx.x;  // 0..63
    const float* __restrict__ row = in + b * K;
    float acc = bias[j];
    #pragma unroll 8
    for (int k = 0; k < K; ++k)
        acc = fmaf(row[k], W[k * NOUT + j], acc);
    acc = fmaxf(acc, 0.f);
    float s = acc, q = acc * acc;
    #pragma unroll
    for (int off = 32; off > 0; off >>= 1) {
        s += __shfl_xor(s, off);
        q += __shfl_xor(q, off);
    }
    const float m   = s * (1.f / BB);
    const float var = q * (1.f / BB) - m * m;
    out[b * NOUT + j] = (acc - m) * rsqrtf(var + EPSV) * g[j] + beta[j];
}

// ---------------------------------------------------------------------------
// Final Linear + row softmax. One block per batch row, 32 threads = classes.
// ---------------------------------------------------------------------------
__global__ void k_head(const float* __restrict__ h,   // [BB, NH2]
                       const float* __restrict__ Wo,  // [NH2, NC]
                       const float* __restrict__ bo,
                       float* __restrict__ y)         // [BB, NC]
{
    const int b = blockIdx.x;
    const int c = threadIdx.x;  // 0..31
    const float* __restrict__ row = h + b * NH2;
    float acc = bo[c];
    #pragma unroll 8
    for (int k = 0; k < NH2; ++k)
        acc = fmaf(row[k], Wo[k * NC + c], acc);
    float mx = acc;
    #pragma unroll
    for (int off = 16; off > 0; off >>= 1)
        mx = fmaxf(mx, __shfl_xor(mx, off));
    const float e = expf(acc - mx);
    float s = e;
    #pragma unroll
    for (int off = 16; off > 0; off >>= 1)
        s += __shfl_xor(s, off);
    y[b * NC + c] = e / s;
}

// ---------------------------------------------------------------------------
extern "C" void kernel_launch(void* const* d_in, const int* in_sizes, int n_in,
                              void* d_out, int out_size, void* d_ws, size_t ws_size,
                              hipStream_t stream)
{
    const float* x    = (const float*)d_in[0];
    const float* w    = (const float*)d_in[1];
    const float* co_w = (const float*)d_in[2];
    const float* bn0g = (const float*)d_in[3];
    const float* bn0b = (const float*)d_in[4];
    const float* W1   = (const float*)d_in[5];
    const float* b1   = (const float*)d_in[6];
    const float* bn1g = (const float*)d_in[7];
    const float* bn1b = (const float*)d_in[8];
    const float* W2   = (const float*)d_in[9];
    const float* b2   = (const float*)d_in[10];
    const float* bn2g = (const float*)d_in[11];
    const float* bn2b = (const float*)d_in[12];
    const float* Wo   = (const float*)d_in[13];
    const float* bo   = (const float*)d_in[14];
    const int*   idx  = (const int*)d_in[15];

    float* out = (float*)d_out;
    float* y   = out;               // [64, 32]  (output 0)
    float* Z   = out + BB * NC;     // [64, 128] (output 1)

    float* WX = (float*)d_ws;       // 8192 f32
    float* h1 = WX + BB * NP;       // 16384 f32
    float* h2 = h1 + BB * NH1;      // 8192 f32

    hipMemsetAsync(WX, 0, BB * NP * sizeof(float), stream);
    k_scatter<<<1024, 256, 0, stream>>>(x, w, idx, WX);
    k_bn0<<<1, NP, 0, stream>>>(WX, co_w, bn0g, bn0b, Z);
    k_fc_bn<NP, NH1><<<NH1, BB, 0, stream>>>(Z, W1, b1, bn1g, bn1b, h1);
    k_fc_bn<NH1, NH2><<<NH2, BB, 0, stream>>>(h1, W2, b2, bn2g, bn2b, h2);
    k_head<<<BB, NC, 0, stream>>>(h2, Wo, bo, y);
}

// Round 6
// 156.701 us; speedup vs baseline: 4.0537x; 1.0139x over previous
//
#include <hip/hip_runtime.h>
#include <hip/hip_bf16.h>

#define BB     64
#define NTOT   800000
#define NF4    200000        // NTOT / 4
#define CHUNKS (NF4 / 64)    // 3125 chunks of 64 float4 per batch-row
#define NP     128
#define NH1    256
#define NH2    128
#define NC     32
#define EPSV   1e-5f
#define BGS    8             // batches per group
#define NGRP   (BB / BGS)    // 8 groups
#define TOTIT  (NGRP * CHUNKS)  // 25000 chunk-iterations

typedef float fx4 __attribute__((ext_vector_type(4)));

__device__ __forceinline__ float dot4(fx4 a, fx4 b) {
    return fmaf(a[0], b[0], fmaf(a[1], b[1], fmaf(a[2], b[2], a[3] * b[3])));
}

__device__ __forceinline__ int bitrev3(int l) {
    return ((l & 1) << 2) | (l & 2) | ((l & 4) >> 2);
}

template <int C, int M>
__device__ __forceinline__ void red_step(float* v, int lane) {
    const bool hi = (lane & M) != 0;
    #pragma unroll
    for (int j = 0; j < C / 2; ++j) {
        float mine  = hi ? v[j + C / 2] : v[j];
        float other = hi ? v[j]         : v[j + C / 2];
        v[j] = mine + __shfl_xor(other, M);
    }
}

// Flush 8 per-thread accumulators: transpose-reduce (15 shuffles) -> one
// atomic from each of lanes 0..7. (Pattern verified in R3/R4 runs.)
__device__ __forceinline__ void flushf(float* acc, int curp, int curbg,
                                       int lane, float* __restrict__ WX) {
    if (curp < 0) return;
    red_step<8, 1>(acc, lane);
    red_step<4, 2>(acc, lane);
    red_step<2, 4>(acc, lane);
    float s = acc[0];
    s += __shfl_xor(s, 8);
    s += __shfl_xor(s, 16);
    s += __shfl_xor(s, 32);
    if (lane < 8)
        atomicAdd(&WX[(curbg * BGS + bitrev3(lane)) * NP + curp], s);
}

// ---------------------------------------------------------------------------
// Scatter-reduce: WX[b, idx[n]] += x[b,n] * w[n]     (idx sorted)
// Each wave owns a CONTIGUOUS run of (batch-group, chunk) iterations.
// A pathway segment spans ~24 consecutive chunks, so the common-path
// iteration is shuffle-free and atomic-free: 10 coalesced loads, 8 dots,
// 8 adds, one ballot. Reduce+atomic only on pathway change / run end.
// ---------------------------------------------------------------------------
__global__ __launch_bounds__(256, 4) void k_scatter(
    const float* __restrict__ x, const float* __restrict__ w,
    const int* __restrict__ idx, float* __restrict__ WX)
{
    const int lane = threadIdx.x & 63;
    const int wid  = (blockIdx.x * 256 + threadIdx.x) >> 6;
    const int nw   = (gridDim.x * 256) >> 6;

    const int start = (int)(((long long)wid       * TOTIT) / nw);
    const int end   = (int)(((long long)(wid + 1) * TOTIT) / nw);
    if (start >= end) return;

    const fx4*  __restrict__ w4 = reinterpret_cast<const fx4*>(w);
    const int4* __restrict__ p4 = reinterpret_cast<const int4*>(idx);
    const fx4*  __restrict__ x4 = reinterpret_cast<const fx4*>(x);

    int bg = start / CHUNKS;
    int c  = start - bg * CHUNKS;

    float acc[BGS];
    int curp = -1, curbg = -1;

    for (int it = start; it < end; ++it) {
        const int n4 = c * 64 + lane;
        const fx4  wv = w4[n4];
        const int4 pv = p4[n4];

        fx4 xr[BGS];
        const size_t base = (size_t)(bg * BGS) * NF4 + n4;
        #pragma unroll
        for (int i = 0; i < BGS; ++i)
            xr[i] = x4[base + (size_t)i * NF4];

        const int  fp  = __builtin_amdgcn_readfirstlane(pv.x);
        const bool uni =
            (__ballot(((pv.x == pv.w) && (pv.x == fp)) ? 1 : 0) == ~0ull);

        float d[BGS];
        #pragma unroll
        for (int i = 0; i < BGS; ++i)
            d[i] = dot4(xr[i], wv);

        if (uni && fp == curp && bg == curbg) {
            #pragma unroll
            for (int i = 0; i < BGS; ++i)
                acc[i] += d[i];                      // common path: no sync ops
        } else {
            flushf(acc, curp, curbg, lane, WX);
            if (uni) {
                curp = fp; curbg = bg;
                #pragma unroll
                for (int i = 0; i < BGS; ++i)
                    acc[i] = d[i];
            } else {                                  // boundary chunk (rare)
                curp = -1;
                #pragma unroll
                for (int i = 0; i < BGS; ++i) {
                    float* row = &WX[(bg * BGS + i) * NP];
                    if (pv.x == pv.w) {
                        atomicAdd(&row[pv.x], d[i]);
                    } else {
                        atomicAdd(&row[pv.x], xr[i][0] * wv[0]);
                        atomicAdd(&row[pv.y], xr[i][1] * wv[1]);
                        atomicAdd(&row[pv.z], xr[i][2] * wv[2]);
                        atomicAdd(&row[pv.w], xr[i][3] * wv[3]);
                    }
                }
            }
        }
        if (++c == CHUNKS) { c = 0; ++bg; }
    }
    flushf(acc, curp, curbg, lane, WX);
}

// ---------------------------------------------------------------------------
// BN0 (batch stats over axis 0) + CancelOut sigmoid gate. One block, 128 thr.
// ---------------------------------------------------------------------------
__global__ void k_bn0(const float* __restrict__ WX,
                      const float* __restrict__ co_w,
                      const float* __restrict__ g,
                      const float* __restrict__ beta,
                      float* __restrict__ Z)
{
    const int p = threadIdx.x;  // 0..127
    float sum = 0.f, sq = 0.f;
    for (int b = 0; b < BB; ++b) {
        float r = fmaxf(WX[b * NP + p], 0.f);
        sum += r; sq += r * r;
    }
    const float m   = sum * (1.f / BB);
    const float var = sq * (1.f / BB) - m * m;
    const float sc  = rsqrtf(var + EPSV) * g[p];
    const float bt  = beta[p];
    const float sig = 1.f / (1.f + expf(-co_w[p]));
    for (int b = 0; b < BB; ++b) {
        float r = fmaxf(WX[b * NP + p], 0.f);
        Z[b * NP + p] = ((r - m) * sc + bt) * sig;
    }
}

// ---------------------------------------------------------------------------
// Linear -> ReLU -> BN(batch stats). One block per output column j,
// 64 threads = 1 wave = the batch dim -> BN stats via wave shuffle.
// ---------------------------------------------------------------------------
template <int K, int NOUT>
__global__ void k_fc_bn(const float* __restrict__ in,    // [BB, K]
                        const float* __restrict__ W,     // [K, NOUT]
                        const float* __restrict__ bias,
                        const float* __restrict__ g,
                        const float* __restrict__ beta,
                        float* __restrict__ out)         // [BB, NOUT]
{
    const int j = blockIdx.x;
    const int b = threadIdx.x;  // 0..63
    const float* __restrict__ row = in + b * K;
    float acc = bias[j];
    #pragma unroll 8
    for (int k = 0; k < K; ++k)
        acc = fmaf(row[k], W[k * NOUT + j], acc);
    acc = fmaxf(acc, 0.f);
    float s = acc, q = acc * acc;
    #pragma unroll
    for (int off = 32; off > 0; off >>= 1) {
        s += __shfl_xor(s, off);
        q += __shfl_xor(q, off);
    }
    const float m   = s * (1.f / BB);
    const float var = q * (1.f / BB) - m * m;
    out[b * NOUT + j] = (acc - m) * rsqrtf(var + EPSV) * g[j] + beta[j];
}

// ---------------------------------------------------------------------------
// Final Linear + row softmax. One block per batch row, 32 threads = classes.
// ---------------------------------------------------------------------------
__global__ void k_head(const float* __restrict__ h,   // [BB, NH2]
                       const float* __restrict__ Wo,  // [NH2, NC]
                       const float* __restrict__ bo,
                       float* __restrict__ y)         // [BB, NC]
{
    const int b = blockIdx.x;
    const int c = threadIdx.x;  // 0..31
    const float* __restrict__ row = h + b * NH2;
    float acc = bo[c];
    #pragma unroll 8
    for (int k = 0; k < NH2; ++k)
        acc = fmaf(row[k], Wo[k * NC + c], acc);
    float mx = acc;
    #pragma unroll
    for (int off = 16; off > 0; off >>= 1)
        mx = fmaxf(mx, __shfl_xor(mx, off));
    const float e = expf(acc - mx);
    float s = e;
    #pragma unroll
    for (int off = 16; off > 0; off >>= 1)
        s += __shfl_xor(s, off);
    y[b * NC + c] = e / s;
}

// ---------------------------------------------------------------------------
extern "C" void kernel_launch(void* const* d_in, const int* in_sizes, int n_in,
                              void* d_out, int out_size, void* d_ws, size_t ws_size,
                              hipStream_t stream)
{
    const float* x    = (const float*)d_in[0];
    const float* w    = (const float*)d_in[1];
    const float* co_w = (const float*)d_in[2];
    const float* bn0g = (const float*)d_in[3];
    const float* bn0b = (const float*)d_in[4];
    const float* W1   = (const float*)d_in[5];
    const float* b1   = (const float*)d_in[6];
    const float* bn1g = (const float*)d_in[7];
    const float* bn1b = (const float*)d_in[8];
    const float* W2   = (const float*)d_in[9];
    const float* b2   = (const float*)d_in[10];
    const float* bn2g = (const float*)d_in[11];
    const float* bn2b = (const float*)d_in[12];
    const float* Wo   = (const float*)d_in[13];
    const float* bo   = (const float*)d_in[14];
    const int*   idx  = (const int*)d_in[15];

    float* out = (float*)d_out;
    float* y   = out;               // [64, 32]  (output 0)
    float* Z   = out + BB * NC;     // [64, 128] (output 1)

    float* WX = (float*)d_ws;       // 8192 f32
    float* h1 = WX + BB * NP;       // 16384 f32
    float* h2 = h1 + BB * NH1;      // 8192 f32

    hipMemsetAsync(WX, 0, BB * NP * sizeof(float), stream);
    k_scatter<<<1024, 256, 0, stream>>>(x, w, idx, WX);
    k_bn0<<<1, NP, 0, stream>>>(WX, co_w, bn0g, bn0b, Z);
    k_fc_bn<NP, NH1><<<NH1, BB, 0, stream>>>(Z, W1, b1, bn1g, bn1b, h1);
    k_fc_bn<NH1, NH2><<<NH2, BB, 0, stream>>>(h1, W2, b2, bn2g, bn2b, h2);
    k_head<<<BB, NC, 0, stream>>>(h2, Wo, bo, y);
}

// Round 7
// 89.104 us; speedup vs baseline: 7.1290x; 1.7586x over previous
//
#include <hip/hip_runtime.h>
#include <hip/hip_bf16.h>

#define BB     64
#define NF4    200000        // NTOT / 4
#define CHUNKS 3125          // NF4 / 64
#define NP     128
#define NH1    256
#define NH2    128
#define NC     32
#define EPSV   1e-5f

typedef float fx4 __attribute__((ext_vector_type(4)));

#define AS_G __attribute__((address_space(1)))
#define AS_L __attribute__((address_space(3)))

__device__ __forceinline__ float dot4(fx4 a, fx4 b) {
    return fmaf(a[0], b[0], fmaf(a[1], b[1], fmaf(a[2], b[2], a[3] * b[3])));
}

// ---------------------------------------------------------------------------
// Scatter-reduce: WX[b, idx[n]] += x[b,n] * w[n]     (idx sorted)
// One wave per block. Wave owns one 64-quad chunk (256 elements -> at most
// TWO pathways) x 32 batch rows. x is streamed via global_load_lds (width
// 16) into an 8-slot/1KB LDS ring with 7 loads in flight -> zero VGPR
// liveness for the stream, so the compiler cannot serialize it. Boundary
// chunks are handled branch-free with premasked weights wLo/wHi.
// ---------------------------------------------------------------------------
__global__ __launch_bounds__(64) void k_scatter(
    const float* __restrict__ x, const float* __restrict__ w,
    const int* __restrict__ idx, float* __restrict__ WX)
{
    __shared__ char lds[8 * 1024];       // 8 slots x 1KB
    const int lane = threadIdx.x;        // 0..63
    const int wid  = blockIdx.x;         // 0..6249
    const int ch   = wid >> 1;           // chunk id
    const int bh   = (wid & 1) << 5;     // batch-half start: 0 or 32
    const int n4   = ch * 64 + lane;

    const fx4*  __restrict__ w4 = reinterpret_cast<const fx4*>(w);
    const int4* __restrict__ p4 = reinterpret_cast<const int4*>(idx);
    const fx4*  __restrict__ x4 = reinterpret_cast<const fx4*>(x);

    const fx4  wv = w4[n4];
    const int4 pv = p4[n4];
    const int  pLo = __builtin_amdgcn_readfirstlane(pv.x);
    const int  pHi = __shfl(pv.w, 63);   // last element's pathway
    const bool uniform = (pLo == pHi);

    // Premasked weights: element contributes to pLo-chain or pHi-chain.
    fx4 wLo, wHi;
    wLo[0] = (pv.x == pLo) ? wv[0] : 0.f;  wHi[0] = (pv.x == pHi) ? wv[0] : 0.f;
    wLo[1] = (pv.y == pLo) ? wv[1] : 0.f;  wHi[1] = (pv.y == pHi) ? wv[1] : 0.f;
    wLo[2] = (pv.z == pLo) ? wv[2] : 0.f;  wHi[2] = (pv.z == pHi) ? wv[2] : 0.f;
    wLo[3] = (pv.w == pLo) ? wv[3] : 0.f;  wHi[3] = (pv.w == pHi) ? wv[3] : 0.f;

    // Prologue: 7 loads in flight (slots 0..6).
    #pragma unroll
    for (int i = 0; i < 7; ++i) {
        const float* gp = (const float*)(x4 + ((size_t)(bh + i) * NF4 + n4));
        __builtin_amdgcn_global_load_lds((const AS_G float*)gp,
                                         (AS_L float*)(lds + i * 1024), 16, 0, 0);
    }

    #pragma unroll
    for (int i = 0; i < 32; ++i) {
        if (i < 25) {
            // Wait until <=6 vmem outstanding: guarantees slot (i&7) landed.
            asm volatile("s_waitcnt vmcnt(6)" ::: "memory");
        } else if (i == 25) {
            asm volatile("s_waitcnt vmcnt(0)" ::: "memory");  // ring tail drain
        }
        __builtin_amdgcn_sched_barrier(0);

        const fx4 xr = *reinterpret_cast<const fx4*>(lds + (i & 7) * 1024 + lane * 16);
        float sLo = dot4(xr, wLo);
        if (uniform) {
            #pragma unroll
            for (int off = 1; off < 64; off <<= 1)
                sLo += __shfl_xor(sLo, off);
            if (lane == 0)
                atomicAdd(&WX[(bh + i) * NP + pLo], sLo);
        } else {
            float sHi = dot4(xr, wHi);
            #pragma unroll
            for (int off = 1; off < 64; off <<= 1) {
                sLo += __shfl_xor(sLo, off);
                sHi += __shfl_xor(sHi, off);
            }
            if (lane == 0) {
                atomicAdd(&WX[(bh + i) * NP + pLo], sLo);
                atomicAdd(&WX[(bh + i) * NP + pHi], sHi);
            }
        }
        __builtin_amdgcn_sched_barrier(0);

        if (i < 25) {   // refill: slot (i+7)&7 == (i-1)&7, consumed last iter
            const float* gp = (const float*)(x4 + ((size_t)(bh + i + 7) * NF4 + n4));
            __builtin_amdgcn_global_load_lds((const AS_G float*)gp,
                                             (AS_L float*)(lds + ((i + 7) & 7) * 1024),
                                             16, 0, 0);
        }
        __builtin_amdgcn_sched_barrier(0);
    }
}

// ---------------------------------------------------------------------------
// BN0 (batch stats over axis 0) + CancelOut sigmoid gate. One block, 128 thr.
// ---------------------------------------------------------------------------
__global__ void k_bn0(const float* __restrict__ WX,
                      const float* __restrict__ co_w,
                      const float* __restrict__ g,
                      const float* __restrict__ beta,
                      float* __restrict__ Z)
{
    const int p = threadIdx.x;  // 0..127
    float sum = 0.f, sq = 0.f;
    for (int b = 0; b < BB; ++b) {
        float r = fmaxf(WX[b * NP + p], 0.f);
        sum += r; sq += r * r;
    }
    const float m   = sum * (1.f / BB);
    const float var = sq * (1.f / BB) - m * m;
    const float sc  = rsqrtf(var + EPSV) * g[p];
    const float bt  = beta[p];
    const float sig = 1.f / (1.f + expf(-co_w[p]));
    for (int b = 0; b < BB; ++b) {
        float r = fmaxf(WX[b * NP + p], 0.f);
        Z[b * NP + p] = ((r - m) * sc + bt) * sig;
    }
}

// ---------------------------------------------------------------------------
// Linear -> ReLU -> BN(batch stats). One block per output column j,
// 64 threads = 1 wave = the batch dim -> BN stats via wave shuffle.
// ---------------------------------------------------------------------------
template <int K, int NOUT>
__global__ void k_fc_bn(const float* __restrict__ in,    // [BB, K]
                        const float* __restrict__ W,     // [K, NOUT]
                        const float* __restrict__ bias,
                        const float* __restrict__ g,
                        const float* __restrict__ beta,
                        float* __restrict__ out)         // [BB, NOUT]
{
    const int j = blockIdx.x;
    const int b = threadIdx.x;  // 0..63
    const float* __restrict__ row = in + b * K;
    float acc = bias[j];
    #pragma unroll 8
    for (int k = 0; k < K; ++k)
        acc = fmaf(row[k], W[k * NOUT + j], acc);
    acc = fmaxf(acc, 0.f);
    float s = acc, q = acc * acc;
    #pragma unroll
    for (int off = 32; off > 0; off >>= 1) {
        s += __shfl_xor(s, off);
        q += __shfl_xor(q, off);
    }
    const float m   = s * (1.f / BB);
    const float var = q * (1.f / BB) - m * m;
    out[b * NOUT + j] = (acc - m) * rsqrtf(var + EPSV) * g[j] + beta[j];
}

// ---------------------------------------------------------------------------
// Final Linear + row softmax. One block per batch row, 32 threads = classes.
// ---------------------------------------------------------------------------
__global__ void k_head(const float* __restrict__ h,   // [BB, NH2]
                       const float* __restrict__ Wo,  // [NH2, NC]
                       const float* __restrict__ bo,
                       float* __restrict__ y)         // [BB, NC]
{
    const int b = blockIdx.x;
    const int c = threadIdx.x;  // 0..31
    const float* __restrict__ row = h + b * NH2;
    float acc = bo[c];
    #pragma unroll 8
    for (int k = 0; k < NH2; ++k)
        acc = fmaf(row[k], Wo[k * NC + c], acc);
    float mx = acc;
    #pragma unroll
    for (int off = 16; off > 0; off >>= 1)
        mx = fmaxf(mx, __shfl_xor(mx, off));
    const float e = expf(acc - mx);
    float s = e;
    #pragma unroll
    for (int off = 16; off > 0; off >>= 1)
        s += __shfl_xor(s, off);
    y[b * NC + c] = e / s;
}

// ---------------------------------------------------------------------------
extern "C" void kernel_launch(void* const* d_in, const int* in_sizes, int n_in,
                              void* d_out, int out_size, void* d_ws, size_t ws_size,
                              hipStream_t stream)
{
    const float* x    = (const float*)d_in[0];
    const float* w    = (const float*)d_in[1];
    const float* co_w = (const float*)d_in[2];
    const float* bn0g = (const float*)d_in[3];
    const float* bn0b = (const float*)d_in[4];
    const float* W1   = (const float*)d_in[5];
    const float* b1   = (const float*)d_in[6];
    const float* bn1g = (const float*)d_in[7];
    const float* bn1b = (const float*)d_in[8];
    const float* W2   = (const float*)d_in[9];
    const float* b2   = (const float*)d_in[10];
    const float* bn2g = (const float*)d_in[11];
    const float* bn2b = (const float*)d_in[12];
    const float* Wo   = (const float*)d_in[13];
    const float* bo   = (const float*)d_in[14];
    const int*   idx  = (const int*)d_in[15];

    float* out = (float*)d_out;
    float* y   = out;               // [64, 32]  (output 0)
    float* Z   = out + BB * NC;     // [64, 128] (output 1)

    float* WX = (float*)d_ws;       // 8192 f32
    float* h1 = WX + BB * NP;       // 16384 f32
    float* h2 = h1 + BB * NH1;      // 8192 f32

    hipMemsetAsync(WX, 0, BB * NP * sizeof(float), stream);
    k_scatter<<<CHUNKS * 2, 64, 0, stream>>>(x, w, idx, WX);
    k_bn0<<<1, NP, 0, stream>>>(WX, co_w, bn0g, bn0b, Z);
    k_fc_bn<NP, NH1><<<NH1, BB, 0, stream>>>(Z, W1, b1, bn1g, bn1b, h1);
    k_fc_bn<NH1, NH2><<<NH2, BB, 0, stream>>>(h1, W2, b2, bn2g, bn2b, h2);
    k_head<<<BB, NC, 0, stream>>>(h2, Wo, bo, y);
}